// Round 12
// baseline (455.003 us; speedup 1.0000x reference)
//
#include <hip/hip_runtime.h>
#include <math.h>

#define B_ 8
#define C_ 256
#define NPIX 4096      // 64*64
#define NP 1024        // 32*32

typedef __attribute__((ext_vector_type(8))) short bf16x8;
typedef __attribute__((ext_vector_type(4))) float f32x4;

#define GLL16(src, dst) __builtin_amdgcn_global_load_lds( \
    (__attribute__((address_space(1))) void*)(src), \
    (__attribute__((address_space(3))) void*)(dst), 16, 0, 0)

#define MFMA16(a, b, c) __builtin_amdgcn_mfma_f32_16x16x32_bf16((a), (b), (c), 0, 0, 0)

__device__ __forceinline__ unsigned short f2bf(float f) {
  unsigned int u = __float_as_uint(f);
  unsigned int r = (u + 0x7FFFu + ((u >> 16) & 1u)) >> 16;
  return (unsigned short)r;
}
__device__ __forceinline__ unsigned int pk2(unsigned short lo, unsigned short hi) {
  return (unsigned int)lo | ((unsigned int)hi << 16);
}

// ---------- reductions ----------
__device__ __forceinline__ float wave_reduce_sum(float v) {
#pragma unroll
  for (int off = 32; off > 0; off >>= 1) v += __shfl_down(v, off, 64);
  return v;
}
__device__ __forceinline__ float wave_reduce_max(float v) {
#pragma unroll
  for (int off = 32; off > 0; off >>= 1) v = fmaxf(v, __shfl_down(v, off, 64));
  return v;
}

// ---------- bilinear resize, align_corners=True (mask 256->64 only) ----------
__global__ __launch_bounds__(256) void k_resize(const float* __restrict__ in, float* __restrict__ out,
                                                int IH, int IW, int OH, int OW, int nElem) {
  int idx = blockIdx.x * 256 + threadIdx.x;
  if (idx >= nElem) return;
  int ox = idx % OW; int t = idx / OW; int oy = t % OH; int bc = t / OH;
  float dy = (float)(IH - 1) / (float)(OH - 1);
  float dx = (float)(IW - 1) / (float)(OW - 1);
  float yf = (float)oy * dy;
  float xf = (float)ox * dx;
  float y0f = floorf(yf), x0f = floorf(xf);
  int y0 = (int)y0f, x0 = (int)x0f;
  int y1 = min(y0 + 1, IH - 1), x1 = min(x0 + 1, IW - 1);
  float wy = yf - y0f, wx = xf - x0f;
  const float* p = in + (size_t)bc * IH * IW;
  float a = p[y0 * IW + x0], b = p[y0 * IW + x1];
  float c = p[y1 * IW + x0], d = p[y1 * IW + x1];
  float top = a * (1.0f - wx) + b * wx;
  float bot = c * (1.0f - wx) + d * wx;
  out[idx] = top * (1.0f - wy) + bot * wy;
}

// ---------- weight prep ----------
__global__ __launch_bounds__(256) void k_wprep(const float* __restrict__ Wc, const float* __restrict__ Wm,
                                               const float* __restrict__ Wf,
                                               unsigned short* __restrict__ Wp1, unsigned short* __restrict__ Wp2) {
  int idx = blockIdx.x * 256 + threadIdx.x;
  if (idx >= 3 * 589824) return;
  int part = idx / 589824;
  int rem = idx % 589824;
  int kk = rem >> 16, co = (rem >> 8) & 255, ci = rem & 255;
  const float* W = (part == 0) ? Wc : (part == 1) ? Wm : Wf;
  unsigned short o = f2bf(W[(size_t)co * 2304 + ci * 9 + kk]);
  if (part == 0) Wp1[rem] = o;
  else if (part == 1) Wp1[589824 + rem] = o;
  else Wp2[rem] = o;
}

__global__ __launch_bounds__(256) void k_bias(const float* __restrict__ bc, const float* __restrict__ bm,
                                              float* __restrict__ bias1, float* __restrict__ zpg) {
  int i = threadIdx.x;
  bias1[i] = bc[i] + bm[i];
  for (int j = i; j < 2048; j += 256) zpg[j] = 0.f;
}

// ---------- A prep TRANSPOSED: A0t/A1t [b][pix][ci] bf16 ----------
__global__ __launch_bounds__(256) void k_prepAT(const float* __restrict__ fg, const float* __restrict__ bg,
                                                const float* __restrict__ m64,
                                                unsigned short* __restrict__ A0t, unsigned short* __restrict__ A1t) {
  __shared__ unsigned short T0[64][66];
  __shared__ unsigned short T1[64][66];
  int pt = blockIdx.x, ct = blockIdx.y, b = blockIdx.z;
  int pix0 = pt << 6, ci0 = ct << 6;
  int tid = threadIdx.x;
  {
    int r = tid >> 2, c4 = (tid & 3) << 4;
    size_t ib = (((size_t)(b * 256 + ci0 + r)) << 12) + pix0 + c4;
    const float* fb = fg + ib;
    const float* gb = bg + ib;
    const float* mb = m64 + (((size_t)b) << 12) + pix0 + c4;
#pragma unroll
    for (int k = 0; k < 16; k += 4) {
      float4 f = *(const float4*)(fb + k);
      float4 g = *(const float4*)(gb + k);
      float4 m = *(const float4*)(mb + k);
      float s0 = f.x + g.x, s1 = f.y + g.y, s2 = f.z + g.z, s3 = f.w + g.w;
      T0[r][c4 + k + 0] = f2bf(s0 * (1.f - m.x));
      T0[r][c4 + k + 1] = f2bf(s1 * (1.f - m.y));
      T0[r][c4 + k + 2] = f2bf(s2 * (1.f - m.z));
      T0[r][c4 + k + 3] = f2bf(s3 * (1.f - m.w));
      T1[r][c4 + k + 0] = f2bf(s0 * m.x);
      T1[r][c4 + k + 1] = f2bf(s1 * m.y);
      T1[r][c4 + k + 2] = f2bf(s2 * m.z);
      T1[r][c4 + k + 3] = f2bf(s3 * m.w);
    }
  }
  __syncthreads();
  {
    int pr = tid >> 2, cc = (tid & 3) << 4;
    unsigned int o0[8], o1[8];
#pragma unroll
    for (int k = 0; k < 8; k++) {
      o0[k] = pk2(T0[cc + 2 * k][pr], T0[cc + 2 * k + 1][pr]);
      o1[k] = pk2(T1[cc + 2 * k][pr], T1[cc + 2 * k + 1][pr]);
    }
    size_t ob = ((((size_t)b << 12) + pix0 + pr) << 8) + ci0 + cc;
    *(uint4*)&A0t[ob] = *(uint4*)&o0[0];
    *(uint4*)&A0t[ob + 8] = *(uint4*)&o0[4];
    *(uint4*)&A1t[ob] = *(uint4*)&o1[0];
    *(uint4*)&A1t[ob + 8] = *(uint4*)&o1[4];
  }
}

// ---------- LDS fragment swizzle ----------
__device__ __forceinline__ int swz(int row, int slot) {
  return row * 32 + ((slot ^ (row & 3) ^ ((row >> 2) & 3)) << 3);   // ushort units
}

// ---------- conv implicit-GEMM, 2-phase, BK=64, B direct-to-register PREFETCHED 1 chunk ----------
template <int NKK, bool OUT_TRANS_BF16>
__global__ __launch_bounds__(256, 2) void k_conv_bd(const unsigned short* __restrict__ A0t,
                                                    const unsigned short* __restrict__ A1t,
                                                    const unsigned short* __restrict__ Wp,
                                                    const float* __restrict__ bias,
                                                    const unsigned short* __restrict__ zp,
                                                    void* __restrict__ outp) {
  __shared__ __align__(16) unsigned short AB[2][8192];   // [buf][A_k0 4096 | A_k1 4096]
  int wgl = blockIdx.x + 32 * (blockIdx.y + 2 * blockIdx.z);     // grid (32,2,8)
  int nid = (wgl & 7) * 64 + (wgl >> 3);                         // XCD-chunked
  int bp = nid & 31, cot = (nid >> 5) & 1, b = nid >> 6;
  int tid = threadIdx.x, lane = tid & 63, w3 = tid >> 6;
  int wm = w3 >> 1, wn = w3 & 1;

  int rA = w3 * 32 + (lane >> 2), rA1 = rA + 16;
  int ds0 = (lane & 3) ^ (rA & 3) ^ ((rA >> 2) & 3);
  int ds1 = (lane & 3) ^ (rA1 & 3) ^ ((rA1 >> 2) & 3);
  int y_0 = bp * 2 + (rA >> 6), x_0 = rA & 63;
  int y_1 = bp * 2 + (rA1 >> 6), x_1 = rA1 & 63;

  int slot = lane >> 4;
  int mr = wm * 64 + (lane & 15), ncc = wn * 64 + (lane & 15);
  const unsigned short* wB = Wp + (size_t)(cot * 128 + ncc) * 256 + slot * 8;

  f32x4 acc[4][4];
#pragma unroll
  for (int i = 0; i < 4; i++)
#pragma unroll
    for (int j = 0; j < 4; j++) acc[i][j] = (f32x4){0.f, 0.f, 0.f, 0.f};

  const unsigned short *pA0, *pA1;
#define UPD(kkv) {                                                              \
    int kk_ = (kkv);                                                            \
    int kw_ = (NKK == 18 && kk_ >= 9) ? kk_ - 9 : kk_;                          \
    const unsigned short* Asrc_ = (NKK == 18 && kk_ >= 9) ? A1t : A0t;          \
    int ky_ = kw_ / 3 - 1, kx_ = kw_ % 3 - 1;                                   \
    int yy0_ = y_0 + ky_, xx0_ = x_0 + kx_;                                     \
    int yy1_ = y_1 + ky_, xx1_ = x_1 + kx_;                                     \
    pA0 = ((unsigned)yy0_ < 64u && (unsigned)xx0_ < 64u)                        \
        ? Asrc_ + ((((size_t)(b << 6) + yy0_) << 6) + xx0_) * 256 + ds0 * 8     \
        : zp + ds0 * 8;                                                         \
    pA1 = ((unsigned)yy1_ < 64u && (unsigned)xx1_ < 64u)                        \
        ? Asrc_ + ((((size_t)(b << 6) + yy1_) << 6) + xx1_) * 256 + ds1 * 8     \
        : zp + ds1 * 8;                                                         \
  }
#define STAGE(c2, buf) {                                                        \
    int ci0_ = ((c2) & 3) << 6;                                                 \
    unsigned short* lb_ = &AB[buf][0];                                          \
    GLL16(pA0 + ci0_,      lb_ + w3 * 1024);                                    \
    GLL16(pA1 + ci0_,      lb_ + w3 * 1024 + 512);                              \
    GLL16(pA0 + ci0_ + 32, lb_ + 4096 + w3 * 1024);                             \
    GLL16(pA1 + ci0_ + 32, lb_ + 4096 + w3 * 1024 + 512);                       \
  }
#define BLOAD(dst, c2) {                                                        \
    const unsigned short* pB_ = wB + ((size_t)((c2) >> 2) << 16) + (((c2) & 3) << 6); \
    _Pragma("unroll")                                                           \
    for (int ks_ = 0; ks_ < 2; ++ks_)                                           \
      _Pragma("unroll")                                                         \
      for (int j_ = 0; j_ < 4; ++j_)                                            \
        dst[ks_][j_] = *(const bf16x8*)(pB_ + ks_ * 32 + j_ * 4096);            \
  }

  const int NCH = NKK * 4;
  UPD(0);
  STAGE(0, 0);                 // A(0): 4 loads
  bf16x8 bA[2][4], bB[2][4];
  BLOAD(bA, 0);                // B(0): 8 loads  -> 12 outstanding
  for (int c = 0; c < NCH; ++c) {
    asm volatile("" ::: "memory");
    __builtin_amdgcn_s_barrier();          // all waves done reading buf[(c+1)&1]
    asm volatile("" ::: "memory");
    if (c < NCH - 1) {
      int cn = c + 1;
      BLOAD(bB, cn);                       // B(c+1): 8 reg loads
      if ((cn & 3) == 0) UPD(cn >> 2);
      STAGE(cn, cn & 1);                   // A(c+1): 4 GLL16
      // queue oldest->newest: B(c)[8], A(c)[4], B(c+1)[8], A(c+1)[4]
      asm volatile("s_waitcnt vmcnt(12)" ::: "memory");   // forces B(c)+A(c) complete
    } else {
      asm volatile("s_waitcnt vmcnt(0)" ::: "memory");
    }
    __builtin_amdgcn_s_barrier();          // buf[c&1] fully staged by all waves
    asm volatile("" ::: "memory");
#pragma unroll
    for (int ks = 0; ks < 2; ++ks) {
      const unsigned short* Al = &AB[c & 1][ks << 12];
      bf16x8 af[4];
#pragma unroll
      for (int i = 0; i < 4; i++) af[i] = *(const bf16x8*)&Al[swz(mr + i * 16, slot)];
#pragma unroll
      for (int i = 0; i < 4; i++)
#pragma unroll
        for (int j = 0; j < 4; j++)
          acc[i][j] = MFMA16(af[i], bA[ks][j], acc[i][j]);
    }
    if (c < NCH - 1) {
#pragma unroll
      for (int ks = 0; ks < 2; ++ks)
#pragma unroll
        for (int j = 0; j < 4; ++j)
          bA[ks][j] = bB[ks][j];
    }
  }
#undef BLOAD
#undef STAGE
#undef UPD

  int px0 = bp * 128 + wm * 64 + ((lane >> 4) << 2);
  int co0 = cot * 128 + wn * 64 + (lane & 15);
#pragma unroll
  for (int j = 0; j < 4; j++) {
    int co = co0 + j * 16;
    float bs = bias[co];
#pragma unroll
    for (int i = 0; i < 4; i++) {
#pragma unroll
      for (int r = 0; r < 4; r++) {
        float v = acc[i][j][r] + bs;
        int pix = px0 + i * 16 + r;
        if (OUT_TRANS_BF16)
          ((unsigned short*)outp)[((((size_t)b << 12) + pix) << 8) + co] = f2bf(v);
        else
          ((float*)outp)[((((size_t)b << 8) + co) << 12) + pix] = v;
      }
    }
  }
}

// ---------- fused instance norm + swish + xd 64->32 downsample ----------
__global__ __launch_bounds__(256) void k_post(float* __restrict__ x, float* __restrict__ xd) {
  __shared__ float sL[4096];
  __shared__ float s4[4];
  int bc = blockIdx.x;
  float* p = x + (size_t)bc * NPIX;
  int tid = threadIdx.x;
  int lane = tid & 63, w = tid >> 6;
  float v[16];
  float s = 0.f;
#pragma unroll
  for (int i = 0; i < 16; i++) { v[i] = p[tid + i * 256]; s += v[i]; }
  s = wave_reduce_sum(s);
  if (lane == 0) s4[w] = s;
  __syncthreads();
  float mean = (s4[0] + s4[1] + s4[2] + s4[3]) * (1.0f / 4096.0f);
  __syncthreads();
  float s2 = 0.f;
#pragma unroll
  for (int i = 0; i < 16; i++) { float d = v[i] - mean; s2 += d * d; }
  s2 = wave_reduce_sum(s2);
  if (lane == 0) s4[w] = s2;
  __syncthreads();
  float var = (s4[0] + s4[1] + s4[2] + s4[3]) * (1.0f / 4096.0f);
  float inv = 1.0f / sqrtf(var + 1e-5f);
#pragma unroll
  for (int i = 0; i < 16; i++) {
    float xn = (v[i] - mean) * inv;
    float sg = 1.0f / (1.0f + expf(-xn));
    float o = xn * sg;
    p[tid + i * 256] = o;
    sL[tid + i * 256] = o;
  }
  __syncthreads();
  float dyx = 63.0f / 31.0f;
  float* xdp = xd + (size_t)bc * NP;
#pragma unroll
  for (int k = 0; k < 4; k++) {
    int q = tid + k * 256;
    int yq = q >> 5, xq = q & 31;
    float yf = (float)yq * dyx;
    float xf = (float)xq * dyx;
    float y0f = floorf(yf), x0f = floorf(xf);
    int y0 = (int)y0f, x0 = (int)x0f;
    int y1 = min(y0 + 1, 63), x1 = min(x0 + 1, 63);
    float wy = yf - y0f, wx = xf - x0f;
    float a = sL[y0 * 64 + x0], b2 = sL[y0 * 64 + x1];
    float c2 = sL[y1 * 64 + x0], d2 = sL[y1 * 64 + x1];
    float top = a * (1.0f - wx) + b2 * wx;
    float bot = c2 * (1.0f - wx) + d2 * wx;
    xdp[q] = top * (1.0f - wy) + bot * wy;
  }
}

// ---------- xd f32 [b][ci][qpix] -> xdt bf16 [b][qpix][ci] ----------
__global__ __launch_bounds__(256) void k_trans_xd(const float* __restrict__ xd,
                                                  unsigned short* __restrict__ xdt) {
  __shared__ unsigned short T[64][66];
  int qt = blockIdx.x, ct = blockIdx.y, b = blockIdx.z;
  int q0 = qt << 6, ci0 = ct << 6;
  int tid = threadIdx.x;
  {
    int r = tid >> 2, c4 = (tid & 3) << 4;
    const float* xb = xd + (((size_t)(b * 256 + ci0 + r)) << 10) + q0 + c4;
#pragma unroll
    for (int k = 0; k < 16; k += 4) {
      float4 f = *(const float4*)(xb + k);
      T[r][c4 + k + 0] = f2bf(f.x);
      T[r][c4 + k + 1] = f2bf(f.y);
      T[r][c4 + k + 2] = f2bf(f.z);
      T[r][c4 + k + 3] = f2bf(f.w);
    }
  }
  __syncthreads();
  {
    int qr = tid >> 2, cc = (tid & 3) << 4;
    unsigned int o[8];
#pragma unroll
    for (int k = 0; k < 8; k++) o[k] = pk2(T[cc + 2 * k][qr], T[cc + 2 * k + 1][qr]);
    size_t ob = ((((size_t)b << 10) + q0 + qr) << 8) + ci0 + cc;
    *(uint4*)&xdt[ob] = *(uint4*)&o[0];
    *(uint4*)&xdt[ob + 8] = *(uint4*)&o[4];
  }
}

// ---------- per-pixel channel sum of squares ----------
__global__ __launch_bounds__(256) void k_sq32(const float* __restrict__ xd, float* __restrict__ sq) {
  int idx = blockIdx.x * 256 + threadIdx.x;
  if (idx >= B_ * NP) return;
  int pix = idx & 1023; int b = idx >> 10;
  const float* p = xd + (size_t)b * C_ * NP + pix;
  float s = 0.f;
  for (int c = 0; c < C_; c++) { float v = p[c * NP]; s += v * v; }
  sq[idx] = s;
}

// ---------- fq[q] = mm ? 1/max(norm,1e-4) : 0 ----------
__global__ __launch_bounds__(256) void k_fq(const float* __restrict__ sq, const float* __restrict__ m64,
                                            float* __restrict__ fq) {
  int idx = blockIdx.x * 256 + threadIdx.x;
  if (idx >= B_ * NP) return;
  int q = idx & 1023, b = idx >> 10;
  int qi = q >> 5, qj = q & 31;
  const float* mb = m64 + (b << 12);
  float dyx = 63.0f / 31.0f;
  float ns = 0.f, ms = 0.f;
#pragma unroll
  for (int k = 0; k < 3; k++)
#pragma unroll
    for (int l = 0; l < 3; l++) {
      int r = qi + k - 1, c = qj + l - 1;
      if (r >= 0 && r < 32 && c >= 0 && c < 32) {
        ns += sq[b * NP + r * 32 + c];
        float yf = (float)r * dyx, xf = (float)c * dyx;
        float y0f = floorf(yf), x0f = floorf(xf);
        int y0 = (int)y0f, x0 = (int)x0f;
        int y1 = min(y0 + 1, 63), x1 = min(x0 + 1, 63);
        float wy = yf - y0f, wx = xf - x0f;
        float a = mb[y0 * 64 + x0], b2 = mb[y0 * 64 + x1];
        float c2 = mb[y1 * 64 + x0], d2 = mb[y1 * 64 + x1];
        float top = a * (1.0f - wx) + b2 * wx;
        float bot = c2 * (1.0f - wx) + d2 * wx;
        ms += top * (1.0f - wy) + bot * wy;
      }
    }
  float f = (ms == 0.0f) ? (1.0f / fmaxf(sqrtf(ns), 1e-4f)) : 0.0f;
  fq[idx] = f;
}

// ---------- Gram, 2-phase GLL16 pipeline BK=64 (R8 verbatim) ----------
__global__ __launch_bounds__(256, 2) void k_gram2ph(const unsigned short* __restrict__ xdt,
                                                    const float* __restrict__ fq,
                                                    const unsigned short* __restrict__ zp,
                                                    float* __restrict__ sc) {
  __shared__ __align__(16) unsigned short AB[2][16384];
  int wgl = blockIdx.x + 8 * (blockIdx.y + 8 * blockIdx.z);
  int nid = (wgl & 7) * 64 + (wgl >> 3);
  int bp = nid & 7, bq = (nid >> 3) & 7, b = nid >> 6;
  int tid = threadIdx.x, lane = tid & 63, w3 = tid >> 6;
  int wm = w3 >> 1, wn = w3 & 1;

  int rA = w3 * 32 + (lane >> 2), rA1 = rA + 16;
  int ds0 = (lane & 3) ^ (rA & 3) ^ ((rA >> 2) & 3);
  int ds1 = (lane & 3) ^ (rA1 & 3) ^ ((rA1 >> 2) & 3);
  int pA0r = bp * 128 + rA, pA1r = bp * 128 + rA1;
  int pB0r = bq * 128 + rA, pB1r = bq * 128 + rA1;
  int piA0 = pA0r >> 5, pjA0 = pA0r & 31, piA1 = pA1r >> 5, pjA1 = pA1r & 31;
  int piB0 = pB0r >> 5, pjB0 = pB0r & 31, piB1 = pB1r >> 5, pjB1 = pB1r & 31;
  const unsigned short* xb = xdt + (((size_t)b) << 18);

  f32x4 acc[4][4];
#pragma unroll
  for (int i = 0; i < 4; i++)
#pragma unroll
    for (int j = 0; j < 4; j++) acc[i][j] = (f32x4){0.f, 0.f, 0.f, 0.f};

  const unsigned short *pA0, *pA1, *pB0, *pB1;

#define GUPDATE(kkv) {                                                          \
    int kk_ = (kkv);                                                            \
    int dy_ = kk_ / 3 - 1, dx_ = kk_ % 3 - 1;                                   \
    int ya0 = piA0 + dy_, xa0 = pjA0 + dx_;                                     \
    int ya1 = piA1 + dy_, xa1 = pjA1 + dx_;                                     \
    int yb0 = piB0 + dy_, xb0 = pjB0 + dx_;                                     \
    int yb1 = piB1 + dy_, xb1 = pjB1 + dx_;                                     \
    pA0 = ((unsigned)ya0 < 32u && (unsigned)xa0 < 32u)                          \
        ? xb + ((((size_t)ya0 << 5) + xa0) << 8) + ds0 * 8 : zp + ds0 * 8;      \
    pA1 = ((unsigned)ya1 < 32u && (unsigned)xa1 < 32u)                          \
        ? xb + ((((size_t)ya1 << 5) + xa1) << 8) + ds1 * 8 : zp + ds1 * 8;      \
    pB0 = ((unsigned)yb0 < 32u && (unsigned)xb0 < 32u)                          \
        ? xb + ((((size_t)yb0 << 5) + xb0) << 8) + ds0 * 8 : zp + ds0 * 8;      \
    pB1 = ((unsigned)yb1 < 32u && (unsigned)xb1 < 32u)                          \
        ? xb + ((((size_t)yb1 << 5) + xb1) << 8) + ds1 * 8 : zp + ds1 * 8;      \
  }
#define GSTAGE(c2, buf) {                                                       \
    int ci0_ = ((c2) & 3) << 6;                                                 \
    unsigned short* lb_ = &AB[buf][0];                                          \
    GLL16(pA0 + ci0_,      lb_ + w3 * 1024);                                    \
    GLL16(pA1 + ci0_,      lb_ + w3 * 1024 + 512);                              \
    GLL16(pA0 + ci0_ + 32, lb_ + 4096 + w3 * 1024);                             \
    GLL16(pA1 + ci0_ + 32, lb_ + 4096 + w3 * 1024 + 512);                       \
    GLL16(pB0 + ci0_,      lb_ + 8192 + w3 * 1024);                             \
    GLL16(pB1 + ci0_,      lb_ + 8192 + w3 * 1024 + 512);                       \
    GLL16(pB0 + ci0_ + 32, lb_ + 12288 + w3 * 1024);                            \
    GLL16(pB1 + ci0_ + 32, lb_ + 12288 + w3 * 1024 + 512);                      \
  }

  GUPDATE(0);
  GSTAGE(0, 0);
  for (int c = 0; c < 36; ++c) {
    asm volatile("" ::: "memory");
    __builtin_amdgcn_s_barrier();
    asm volatile("" ::: "memory");
    if (c < 35) {
      int cn = c + 1;
      if ((cn & 3) == 0) GUPDATE(cn >> 2);
      GSTAGE(cn, cn & 1);
      asm volatile("s_waitcnt vmcnt(8)" ::: "memory");
    } else {
      asm volatile("s_waitcnt vmcnt(0)" ::: "memory");
    }
    __builtin_amdgcn_s_barrier();
    asm volatile("" ::: "memory");
    int slot = lane >> 4;
    int mr = wm * 64 + (lane & 15), ncc = wn * 64 + (lane & 15);
#pragma unroll
    for (int ks = 0; ks < 2; ++ks) {
      const unsigned short* Al = &AB[c & 1][ks << 12];
      const unsigned short* Bl = &AB[c & 1][8192 + (ks << 12)];
      bf16x8 af[4], bfr[4];
#pragma unroll
      for (int i = 0; i < 4; i++) af[i] = *(const bf16x8*)&Al[swz(mr + i * 16, slot)];
#pragma unroll
      for (int j = 0; j < 4; j++) bfr[j] = *(const bf16x8*)&Bl[swz(ncc + j * 16, slot)];
#pragma unroll
      for (int i = 0; i < 4; i++)
#pragma unroll
        for (int j = 0; j < 4; j++)
          acc[i][j] = MFMA16(af[i], bfr[j], acc[i][j]);
    }
  }
#undef GSTAGE
#undef GUPDATE

  int q0 = bq * 128 + wn * 64 + (lane & 15);
  int p0 = bp * 128 + wm * 64 + ((lane >> 4) << 2);
#pragma unroll
  for (int j = 0; j < 4; j++) {
    int q = q0 + j * 16;
    float f = fq[(b << 10) + q];
#pragma unroll
    for (int i = 0; i < 4; i++)
#pragma unroll
      for (int r = 0; r < 4; r++)
        sc[((size_t)(b << 10) + (p0 + i * 16 + r)) * NP + q] = acc[i][j][r] * f;
  }
}

// ---------- softmax over q; emits att bf16 ----------
__global__ __launch_bounds__(256) void k_softmax(const float* __restrict__ sc, const float* __restrict__ fq,
                                                 unsigned short* __restrict__ attb) {
  __shared__ float s4[4];
  int row = blockIdx.x;
  int b = row >> 10;
  const float* r = sc + (size_t)row * NP;
  int tid = threadIdx.x;
  int lane = tid & 63, w = tid >> 6;
  float4 sv = *(const float4*)&r[tid * 4];
  float l0 = sv.x * 10.f, l1 = sv.y * 10.f, l2 = sv.z * 10.f, l3 = sv.w * 10.f;
  float mx = fmaxf(fmaxf(l0, l1), fmaxf(l2, l3));
  mx = wave_reduce_max(mx);
  if (lane == 0) s4[w] = mx;
  __syncthreads();
  float M = fmaxf(fmaxf(s4[0], s4[1]), fmaxf(s4[2], s4[3]));
  __syncthreads();
  float e0 = expf(l0 - M), e1 = expf(l1 - M), e2 = expf(l2 - M), e3 = expf(l3 - M);
  float s = e0 + e1 + e2 + e3;
  s = wave_reduce_sum(s);
  if (lane == 0) s4[w] = s;
  __syncthreads();
  float inv = 1.0f / (s4[0] + s4[1] + s4[2] + s4[3]);
  const float* fb = fq + b * NP + tid * 4;
  float m0 = fb[0] > 0.f ? 1.f : 0.f;
  float m1 = fb[1] > 0.f ? 1.f : 0.f;
  float m2 = fb[2] > 0.f ? 1.f : 0.f;
  float m3 = fb[3] > 0.f ? 1.f : 0.f;
  float a0 = fmaxf(e0 * inv * m0, 1e-8f);
  float a1 = fmaxf(e1 * inv * m1, 1e-8f);
  float a2 = fmaxf(e2 * inv * m2, 1e-8f);
  float a3 = fmaxf(e3 * inv * m3, 1e-8f);
  uint2 o;
  o.x = pk2(f2bf(a0), f2bf(a1));
  o.y = pk2(f2bf(a2), f2bf(a3));
  *(uint2*)&attb[(size_t)row * NP + tid * 4] = o;
}

// ---------- x -> parity-split pre-shifted bf16 copies P0/P1/P2 ----------
__global__ __launch_bounds__(256) void k_xprep(const float* __restrict__ x,
                                               unsigned short* __restrict__ P0,
                                               unsigned short* __restrict__ P1,
                                               unsigned short* __restrict__ P2) {
  int idx = blockIdx.x * 256 + threadIdx.x;
  int xh8 = idx & 3;
  int yh = (idx >> 2) & 31;
  int co = (idx >> 7) & 255;
  int pc = (idx >> 15) & 3;
  int b  = idx >> 17;
  int cy = pc >> 1, cx = pc & 1;
  const float* row = x + ((size_t)(b * 256 + co) * 64 + (2 * yh + cy)) * 64 + 16 * xh8;
  float4 f0 = *(const float4*)(row);
  float4 f1 = *(const float4*)(row + 4);
  float4 f2 = *(const float4*)(row + 8);
  float4 f3 = *(const float4*)(row + 12);
  unsigned short v0 = f2bf(cx ? f0.y : f0.x), v1 = f2bf(cx ? f0.w : f0.z);
  unsigned short v2 = f2bf(cx ? f1.y : f1.x), v3 = f2bf(cx ? f1.w : f1.z);
  unsigned short v4 = f2bf(cx ? f2.y : f2.x), v5 = f2bf(cx ? f2.w : f2.z);
  unsigned short v6 = f2bf(cx ? f3.y : f3.x), v7 = f2bf(cx ? f3.w : f3.z);
  int prev = __shfl_up((int)v7, 1, 64);
  int next = __shfl_down((int)v0, 1, 64);
  unsigned short pv = (xh8 == 0) ? (unsigned short)0 : (unsigned short)prev;
  unsigned short nx = (xh8 == 3) ? (unsigned short)0 : (unsigned short)next;
  size_t base = ((size_t)((b * 4 + pc) * 256 + co) * 32 + yh) * 32 + 8 * xh8;
  uint4 w0 = {pk2(v0, v1), pk2(v2, v3), pk2(v4, v5), pk2(v6, v7)};
  *(uint4*)&P0[base] = w0;
  uint4 w1 = {pk2(pv, v0), pk2(v1, v2), pk2(v3, v4), pk2(v5, v6)};
  *(uint4*)&P1[base] = w1;
  uint4 w2 = {pk2(v1, v2), pk2(v3, v4), pk2(v5, v6), pk2(v7, nx)};
  *(uint4*)&P2[base] = w2;
}

// ---------- PV class-GEMM, 2-phase counted-vmcnt pipeline BK=64 (R8 verbatim) ----------
__global__ __launch_bounds__(256, 2) void k_pv(const unsigned short* __restrict__ attb,
                                               const unsigned short* __restrict__ P0,
                                               const unsigned short* __restrict__ P1,
                                               const unsigned short* __restrict__ P2,
                                               const unsigned short* __restrict__ zp,
                                               const float* __restrict__ xbuf,
                                               const float* __restrict__ m64,
                                               float* __restrict__ out) {
  __shared__ __align__(16) unsigned short AB[2][16384];
  int wg = blockIdx.x + blockIdx.y * 8 + blockIdx.z * 16;
  int nid = (wg & 7) * 64 + (wg >> 3);
  int bn = nid & 7, bm = (nid >> 3) & 1, z = nid >> 4;
  int b = z >> 2, cls = z & 3, cy = cls >> 1, cx = cls & 1;
  int tid = threadIdx.x, lane = tid & 63, w3 = tid >> 6;
  int wm = w3 >> 1, wn = w3 & 1;

  int dy1 = cy ? -1 : 1;
  int pio1 = cy ? 1 : -1;
  int pjo1 = cx ? 1 : -1;
  const unsigned short* Pdx = cx ? P1 : P2;

  int rA0 = w3 * 32 + (lane >> 2);
  int rA1 = rA0 + 16;
  int ds0 = (lane & 3) ^ (rA0 & 3) ^ ((rA0 >> 2) & 3);
  int ds1 = (lane & 3) ^ (rA1 & 3) ^ ((rA1 >> 2) & 3);
  int offA0 = ((z * 256 + bm * 128 + rA0) << 10) + ds0 * 8;
  int offA1 = ((z * 256 + bm * 128 + rA1) << 10) + ds1 * 8;

  const unsigned short* attB = attb + ((size_t)b << 20);
  int o0 = bn * 128 + rA0, o1 = bn * 128 + rA1;
  int oy0 = o0 >> 5, ox0 = o0 & 31, oy1 = o1 >> 5, ox1 = o1 & 31;
#define BPTR(oyv, oxv, dsv, tyv, txv) ({                                        \
    int pi = (oyv) + ((tyv) ? pio1 : 0);                                        \
    int pj = (oxv) + ((txv) ? pjo1 : 0);                                        \
    (pi >= 0 && pi < 32 && pj >= 0 && pj < 32)                                  \
        ? attB + (((pi << 5) + pj) << 10) + (dsv) * 8 : zp; })
  const unsigned short* b0t0 = BPTR(oy0, ox0, ds0, 0, 0);
  const unsigned short* b0t1 = BPTR(oy0, ox0, ds0, 0, 1);
  const unsigned short* b0t2 = BPTR(oy0, ox0, ds0, 1, 0);
  const unsigned short* b0t3 = BPTR(oy0, ox0, ds0, 1, 1);
  const unsigned short* b1t0 = BPTR(oy1, ox1, ds1, 0, 0);
  const unsigned short* b1t1 = BPTR(oy1, ox1, ds1, 0, 1);
  const unsigned short* b1t2 = BPTR(oy1, ox1, ds1, 1, 0);
  const unsigned short* b1t3 = BPTR(oy1, ox1, ds1, 1, 1);
#undef BPTR

  f32x4 acc[4][4];
#pragma unroll
  for (int i = 0; i < 4; i++)
#pragma unroll
    for (int j = 0; j < 4; j++) acc[i][j] = (f32x4){0.f, 0.f, 0.f, 0.f};

  int dA0 = w3 * 1024, dA1 = w3 * 1024 + 512;
  int dB0 = 8192 + w3 * 1024, dB1 = 8192 + w3 * 1024 + 512;

#define PHALF(o2, buf, h) {                                                     \
    int t2 = (o2) >> 5, qi = (o2) & 31;                                         \
    int q32 = qi * 32;                                                          \
    const unsigned short* Ab = (t2 & 1) ? Pdx : P0;                             \
    int dyo = (t2 >> 1) ? dy1 * 32 : 0;                                         \
    bool vA = (t2 < 2) || ((dy1 > 0) ? (qi < 31) : (qi > 0));                   \
    if (!vA) Ab = zp;                                                           \
    int oA0 = vA ? offA0 + dyo + q32 : 0;                                       \
    int oA1 = vA ? offA1 + dyo + q32 : 0;                                       \
    unsigned short* lb = &AB[buf][(h) << 12];                                   \
    GLL16(Ab + oA0, lb + dA0);                                                  \
    GLL16(Ab + oA1, lb + dA1);                                                  \
    const unsigned short* sB0 = (t2 == 0 ? b0t0 : t2 == 1 ? b0t1 : t2 == 2 ? b0t2 : b0t3) + q32; \
    const unsigned short* sB1 = (t2 == 0 ? b1t0 : t2 == 1 ? b1t1 : t2 == 2 ? b1t2 : b1t3) + q32; \
    GLL16(sB0, lb + dB0);                                                       \
    GLL16(sB1, lb + dB1);                                                       \
  }
#define PSTAGE(c2, buf) { PHALF(2 * (c2), buf, 0); PHALF(2 * (c2) + 1, buf, 1); }

  PSTAGE(0, 0);
  for (int c = 0; c < 64; ++c) {
    asm volatile("" ::: "memory");
    __builtin_amdgcn_s_barrier();
    asm volatile("" ::: "memory");
    if (c < 63) {
      PSTAGE(c + 1, (c + 1) & 1);
      asm volatile("s_waitcnt vmcnt(8)" ::: "memory");
    } else {
      asm volatile("s_waitcnt vmcnt(0)" ::: "memory");
    }
    __builtin_amdgcn_s_barrier();
    asm volatile("" ::: "memory");
    int slot = lane >> 4;
    int mr = wm * 64 + (lane & 15), ncc = wn * 64 + (lane & 15);
#pragma unroll
    for (int ks = 0; ks < 2; ++ks) {
      const unsigned short* Al = &AB[c & 1][ks << 12];
      const unsigned short* Bl = &AB[c & 1][8192 + (ks << 12)];
      bf16x8 af[4], bfr[4];
#pragma unroll
      for (int i = 0; i < 4; i++) af[i] = *(const bf16x8*)&Al[swz(mr + i * 16, slot)];
#pragma unroll
      for (int j = 0; j < 4; j++) bfr[j] = *(const bf16x8*)&Bl[swz(ncc + j * 16, slot)];
#pragma unroll
      for (int i = 0; i < 4; i++)
#pragma unroll
        for (int j = 0; j < 4; j++)
          acc[i][j] = MFMA16(af[i], bfr[j], acc[i][j]);
    }
  }
#undef PSTAGE
#undef PHALF

  int co0 = bm * 128 + wm * 64 + ((lane >> 4) << 2);
  int oo0 = bn * 128 + wn * 64 + (lane & 15);
#pragma unroll
  for (int j = 0; j < 4; j++) {
    int o = oo0 + j * 16;
    int oy = ((o >> 5) << 1) + cy, ox = ((o & 31) << 1) + cx;
    int opix = oy * 64 + ox;
    float msk = m64[b * NPIX + opix];
    float s = 0.25f * msk, t1m = 1.0f - msk;
#pragma unroll
    for (int i = 0; i < 4; i++) {
#pragma unroll
      for (int r = 0; r < 4; r++) {
        int co = co0 + i * 16 + r;
        size_t xi = (size_t)(b * C_ + co) * NPIX + opix;
        out[xi] = acc[i][j][r] * s + xbuf[xi] * t1m;
      }
    }
  }
}

extern "C" void kernel_launch(void* const* d_in, const int* in_sizes, int n_in,
                              void* d_out, int out_size, void* d_ws, size_t ws_size,
                              hipStream_t stream) {
  const float* bg   = (const float*)d_in[0];
  const float* fg   = (const float*)d_in[1];
  const float* mask = (const float*)d_in[2];
  const float* Wc   = (const float*)d_in[3];
  const float* bc   = (const float*)d_in[4];
  const float* Wm   = (const float*)d_in[5];
  const float* bm   = (const float*)d_in[6];
  const float* Wf   = (const float*)d_in[7];
  const float* bf   = (const float*)d_in[8];
  float* out = (float*)d_out;
  float* w = (float*)d_ws;

  // workspace (float offsets), total 25,231,360 floats = 100.9 MB
  float* mask64 = w;                          // 32768
  float* sq32   = w + 40960;                  // 8192
  float* fq     = w + 49152;                  // 8192
  float* bias1  = w + 57344;                  // 256
  float* zpage  = w + 57600;                  // 2048 zeros (8 KB)
  unsigned short* A0t = (unsigned short*)(w + 65536);            // [b][pix][ci]
  unsigned short* A1t = (unsigned short*)(w + 65536 + 4194304);
  float* sc = w + 65536;
  unsigned short* P0u = (unsigned short*)(w + 65536);
  unsigned short* P1u = (unsigned short*)(w + 4259840);
  unsigned short* tbuf_t = (unsigned short*)(w + 8454144);       // [b][pix][co]
  float* xd = w + 8454144;
  unsigned short* xdt = (unsigned short*)(w + 10551296);
  unsigned short* attb = (unsigned short*)(w + 8454144);
  float* xbuf = w + 12648448;
  unsigned short* Wp1 = (unsigned short*)(w + 21037056);
  unsigned short* Wp2 = (unsigned short*)(w + 21626880);
  unsigned short* P2u = (unsigned short*)(w + 21037056);

  const unsigned short* zp = (const unsigned short*)zpage;

  hipLaunchKernelGGL(k_resize, dim3(128), dim3(256), 0, stream, mask, mask64, 256, 256, 64, 64, 32768);
  hipLaunchKernelGGL(k_wprep, dim3(6912), dim3(256), 0, stream, Wc, Wm, Wf, Wp1, Wp2);
  hipLaunchKernelGGL(k_bias, dim3(1), dim3(256), 0, stream, bc, bm, bias1, zpage);
  hipLaunchKernelGGL(k_prepAT, dim3(64, 4, 8), dim3(256), 0, stream, fg, bg, mask64, A0t, A1t);
  // conv1 (K=4608) -> tbuf_t bf16 [pix][co], B-direct prefetched
  hipLaunchKernelGGL((k_conv_bd<18, true>), dim3(32, 2, 8), dim3(256), 0, stream,
                     A0t, A1t, Wp1, bias1, zp, (void*)tbuf_t);
  // conv2 (K=2304) -> xbuf f32 [co][pix], B-direct prefetched
  hipLaunchKernelGGL((k_conv_bd<9, false>), dim3(32, 2, 8), dim3(256), 0, stream,
                     tbuf_t, tbuf_t, Wp2, bf, zp, (void*)xbuf);
  hipLaunchKernelGGL(k_post, dim3(B_ * C_), dim3(256), 0, stream, xbuf, xd);
  hipLaunchKernelGGL(k_trans_xd, dim3(16, 4, 8), dim3(256), 0, stream, xd, xdt);
  hipLaunchKernelGGL(k_sq32, dim3(32), dim3(256), 0, stream, xd, sq32);
  hipLaunchKernelGGL(k_fq, dim3(32), dim3(256), 0, stream, sq32, mask64, fq);
  hipLaunchKernelGGL(k_gram2ph, dim3(8, 8, 8), dim3(256), 0, stream, xdt, fq, zp, sc);
  hipLaunchKernelGGL(k_softmax, dim3(B_ * NP), dim3(256), 0, stream, sc, fq, attb);
  hipLaunchKernelGGL(k_xprep, dim3(4096), dim3(256), 0, stream, xbuf, P0u, P1u, P2u);
  hipLaunchKernelGGL(k_pv, dim3(8, 2, 32), dim3(256), 0, stream, attb, P0u, P1u, P2u,
                     zp, xbuf, mask64, out);
}

// Round 13
// 332.884 us; speedup vs baseline: 1.3668x; 1.3668x over previous
//
#include <hip/hip_runtime.h>
#include <math.h>

#define B_ 8
#define C_ 256
#define NPIX 4096      // 64*64
#define NP 1024        // 32*32

typedef __attribute__((ext_vector_type(8))) short bf16x8;
typedef __attribute__((ext_vector_type(4))) float f32x4;

#define GLL16(src, dst) __builtin_amdgcn_global_load_lds( \
    (__attribute__((address_space(1))) void*)(src), \
    (__attribute__((address_space(3))) void*)(dst), 16, 0, 0)

#define MFMA16(a, b, c) __builtin_amdgcn_mfma_f32_16x16x32_bf16((a), (b), (c), 0, 0, 0)

__device__ __forceinline__ unsigned short f2bf(float f) {
  unsigned int u = __float_as_uint(f);
  unsigned int r = (u + 0x7FFFu + ((u >> 16) & 1u)) >> 16;
  return (unsigned short)r;
}
__device__ __forceinline__ unsigned int pk2(unsigned short lo, unsigned short hi) {
  return (unsigned int)lo | ((unsigned int)hi << 16);
}

// ---------- reductions ----------
__device__ __forceinline__ float wave_reduce_sum(float v) {
#pragma unroll
  for (int off = 32; off > 0; off >>= 1) v += __shfl_down(v, off, 64);
  return v;
}
__device__ __forceinline__ float wave_reduce_max(float v) {
#pragma unroll
  for (int off = 32; off > 0; off >>= 1) v = fmaxf(v, __shfl_down(v, off, 64));
  return v;
}

// ---------- bilinear resize, align_corners=True (mask 256->64 only) ----------
__global__ __launch_bounds__(256) void k_resize(const float* __restrict__ in, float* __restrict__ out,
                                                int IH, int IW, int OH, int OW, int nElem) {
  int idx = blockIdx.x * 256 + threadIdx.x;
  if (idx >= nElem) return;
  int ox = idx % OW; int t = idx / OW; int oy = t % OH; int bc = t / OH;
  float dy = (float)(IH - 1) / (float)(OH - 1);
  float dx = (float)(IW - 1) / (float)(OW - 1);
  float yf = (float)oy * dy;
  float xf = (float)ox * dx;
  float y0f = floorf(yf), x0f = floorf(xf);
  int y0 = (int)y0f, x0 = (int)x0f;
  int y1 = min(y0 + 1, IH - 1), x1 = min(x0 + 1, IW - 1);
  float wy = yf - y0f, wx = xf - x0f;
  const float* p = in + (size_t)bc * IH * IW;
  float a = p[y0 * IW + x0], b = p[y0 * IW + x1];
  float c = p[y1 * IW + x0], d = p[y1 * IW + x1];
  float top = a * (1.0f - wx) + b * wx;
  float bot = c * (1.0f - wx) + d * wx;
  out[idx] = top * (1.0f - wy) + bot * wy;
}

// ---------- weight prep (+ fused bias & zero-page init on the extra block) ----------
__global__ __launch_bounds__(256) void k_wprep(const float* __restrict__ Wc, const float* __restrict__ Wm,
                                               const float* __restrict__ Wf,
                                               unsigned short* __restrict__ Wp1, unsigned short* __restrict__ Wp2,
                                               const float* __restrict__ bc, const float* __restrict__ bm,
                                               float* __restrict__ bias1, float* __restrict__ zpg) {
  int blk = blockIdx.x;
  int tid = threadIdx.x;
  if (blk == 6912) {
    bias1[tid] = bc[tid] + bm[tid];
    for (int j = tid; j < 2048; j += 256) zpg[j] = 0.f;
    return;
  }
  int idx = blk * 256 + tid;
  int part = idx / 589824;
  int rem = idx % 589824;
  int kk = rem >> 16, co = (rem >> 8) & 255, ci = rem & 255;
  const float* W = (part == 0) ? Wc : (part == 1) ? Wm : Wf;
  unsigned short o = f2bf(W[(size_t)co * 2304 + ci * 9 + kk]);
  if (part == 0) Wp1[rem] = o;
  else if (part == 1) Wp1[589824 + rem] = o;
  else Wp2[rem] = o;
}

// ---------- A prep TRANSPOSED: A0t/A1t [b][pix][ci] bf16 ----------
__global__ __launch_bounds__(256) void k_prepAT(const float* __restrict__ fg, const float* __restrict__ bg,
                                                const float* __restrict__ m64,
                                                unsigned short* __restrict__ A0t, unsigned short* __restrict__ A1t) {
  __shared__ unsigned short T0[64][66];
  __shared__ unsigned short T1[64][66];
  int pt = blockIdx.x, ct = blockIdx.y, b = blockIdx.z;
  int pix0 = pt << 6, ci0 = ct << 6;
  int tid = threadIdx.x;
  {
    int r = tid >> 2, c4 = (tid & 3) << 4;
    size_t ib = (((size_t)(b * 256 + ci0 + r)) << 12) + pix0 + c4;
    const float* fb = fg + ib;
    const float* gb = bg + ib;
    const float* mb = m64 + (((size_t)b) << 12) + pix0 + c4;
#pragma unroll
    for (int k = 0; k < 16; k += 4) {
      float4 f = *(const float4*)(fb + k);
      float4 g = *(const float4*)(gb + k);
      float4 m = *(const float4*)(mb + k);
      float s0 = f.x + g.x, s1 = f.y + g.y, s2 = f.z + g.z, s3 = f.w + g.w;
      T0[r][c4 + k + 0] = f2bf(s0 * (1.f - m.x));
      T0[r][c4 + k + 1] = f2bf(s1 * (1.f - m.y));
      T0[r][c4 + k + 2] = f2bf(s2 * (1.f - m.z));
      T0[r][c4 + k + 3] = f2bf(s3 * (1.f - m.w));
      T1[r][c4 + k + 0] = f2bf(s0 * m.x);
      T1[r][c4 + k + 1] = f2bf(s1 * m.y);
      T1[r][c4 + k + 2] = f2bf(s2 * m.z);
      T1[r][c4 + k + 3] = f2bf(s3 * m.w);
    }
  }
  __syncthreads();
  {
    int pr = tid >> 2, cc = (tid & 3) << 4;
    unsigned int o0[8], o1[8];
#pragma unroll
    for (int k = 0; k < 8; k++) {
      o0[k] = pk2(T0[cc + 2 * k][pr], T0[cc + 2 * k + 1][pr]);
      o1[k] = pk2(T1[cc + 2 * k][pr], T1[cc + 2 * k + 1][pr]);
    }
    size_t ob = ((((size_t)b << 12) + pix0 + pr) << 8) + ci0 + cc;
    *(uint4*)&A0t[ob] = *(uint4*)&o0[0];
    *(uint4*)&A0t[ob + 8] = *(uint4*)&o0[4];
    *(uint4*)&A1t[ob] = *(uint4*)&o1[0];
    *(uint4*)&A1t[ob + 8] = *(uint4*)&o1[4];
  }
}

// ---------- LDS fragment swizzle ----------
__device__ __forceinline__ int swz(int row, int slot) {
  return row * 32 + ((slot ^ (row & 3) ^ ((row >> 2) & 3)) << 3);   // ushort units
}

// ---------- conv implicit-GEMM, 2-phase GLL16 pipeline, BK=64 (R8 verbatim) ----------
template <int NKK, bool OUT_TRANS_BF16>
__global__ __launch_bounds__(256, 2) void k_conv2ph(const unsigned short* __restrict__ A0t,
                                                    const unsigned short* __restrict__ A1t,
                                                    const unsigned short* __restrict__ Wp,
                                                    const float* __restrict__ bias,
                                                    const unsigned short* __restrict__ zp,
                                                    void* __restrict__ outp) {
  __shared__ __align__(16) unsigned short AB[2][16384];  // [buf][A_k0|A_k1|B_k0|B_k1] 8KB each
  int wgl = blockIdx.x + 32 * (blockIdx.y + 2 * blockIdx.z);     // grid (32,2,8)
  int nid = (wgl & 7) * 64 + (wgl >> 3);                         // XCD-chunk: one b per XCD
  int bp = nid & 31, cot = (nid >> 5) & 1, b = nid >> 6;
  int tid = threadIdx.x, lane = tid & 63, w3 = tid >> 6;
  int wm = w3 >> 1, wn = w3 & 1;

  int rA = w3 * 32 + (lane >> 2), rA1 = rA + 16;
  int ds0 = (lane & 3) ^ (rA & 3) ^ ((rA >> 2) & 3);
  int ds1 = (lane & 3) ^ (rA1 & 3) ^ ((rA1 >> 2) & 3);
  int y_0 = bp * 2 + (rA >> 6), x_0 = rA & 63;
  int y_1 = bp * 2 + (rA1 >> 6), x_1 = rA1 & 63;
  int co_0 = cot * 128 + rA, co_1 = cot * 128 + rA1;

  f32x4 acc[4][4];
#pragma unroll
  for (int i = 0; i < 4; i++)
#pragma unroll
    for (int j = 0; j < 4; j++) acc[i][j] = (f32x4){0.f, 0.f, 0.f, 0.f};

  const unsigned short *pA0, *pA1, *pB0, *pB1;

#define UPDATE(kkv) {                                                           \
    int kk_ = (kkv);                                                            \
    int kw_ = (NKK == 18 && kk_ >= 9) ? kk_ - 9 : kk_;                          \
    const unsigned short* Asrc_ = (NKK == 18 && kk_ >= 9) ? A1t : A0t;          \
    int ky_ = kw_ / 3 - 1, kx_ = kw_ % 3 - 1;                                   \
    int yy0_ = y_0 + ky_, xx0_ = x_0 + kx_;                                     \
    int yy1_ = y_1 + ky_, xx1_ = x_1 + kx_;                                     \
    pA0 = ((unsigned)yy0_ < 64u && (unsigned)xx0_ < 64u)                        \
        ? Asrc_ + ((((size_t)(b << 6) + yy0_) << 6) + xx0_) * 256 + ds0 * 8     \
        : zp + ds0 * 8;                                                         \
    pA1 = ((unsigned)yy1_ < 64u && (unsigned)xx1_ < 64u)                        \
        ? Asrc_ + ((((size_t)(b << 6) + yy1_) << 6) + xx1_) * 256 + ds1 * 8     \
        : zp + ds1 * 8;                                                         \
    pB0 = Wp + ((size_t)kk_ << 16) + co_0 * 256 + ds0 * 8;                      \
    pB1 = Wp + ((size_t)kk_ << 16) + co_1 * 256 + ds1 * 8;                      \
  }
#define STAGE(c2, buf) {                                                        \
    int ci0_ = ((c2) & 3) << 6;                                                 \
    unsigned short* lb_ = &AB[buf][0];                                          \
    GLL16(pA0 + ci0_,      lb_ + w3 * 1024);                                    \
    GLL16(pA1 + ci0_,      lb_ + w3 * 1024 + 512);                              \
    GLL16(pA0 + ci0_ + 32, lb_ + 4096 + w3 * 1024);                             \
    GLL16(pA1 + ci0_ + 32, lb_ + 4096 + w3 * 1024 + 512);                       \
    GLL16(pB0 + ci0_,      lb_ + 8192 + w3 * 1024);                             \
    GLL16(pB1 + ci0_,      lb_ + 8192 + w3 * 1024 + 512);                       \
    GLL16(pB0 + ci0_ + 32, lb_ + 12288 + w3 * 1024);                            \
    GLL16(pB1 + ci0_ + 32, lb_ + 12288 + w3 * 1024 + 512);                      \
  }

  const int NCH = NKK * 4;
  UPDATE(0);
  STAGE(0, 0);
  for (int c = 0; c < NCH; ++c) {
    asm volatile("" ::: "memory");
    __builtin_amdgcn_s_barrier();
    asm volatile("" ::: "memory");
    if (c < NCH - 1) {
      int cn = c + 1;
      if ((cn & 3) == 0) UPDATE(cn >> 2);
      STAGE(cn, cn & 1);
      asm volatile("s_waitcnt vmcnt(8)" ::: "memory");
    } else {
      asm volatile("s_waitcnt vmcnt(0)" ::: "memory");
    }
    __builtin_amdgcn_s_barrier();
    asm volatile("" ::: "memory");
    int slot = lane >> 4;
    int mr = wm * 64 + (lane & 15), ncc = wn * 64 + (lane & 15);
#pragma unroll
    for (int ks = 0; ks < 2; ++ks) {
      const unsigned short* Al = &AB[c & 1][ks << 12];
      const unsigned short* Bl = &AB[c & 1][8192 + (ks << 12)];
      bf16x8 af[4], bfr[4];
#pragma unroll
      for (int i = 0; i < 4; i++) af[i] = *(const bf16x8*)&Al[swz(mr + i * 16, slot)];
#pragma unroll
      for (int j = 0; j < 4; j++) bfr[j] = *(const bf16x8*)&Bl[swz(ncc + j * 16, slot)];
#pragma unroll
      for (int i = 0; i < 4; i++)
#pragma unroll
        for (int j = 0; j < 4; j++)
          acc[i][j] = MFMA16(af[i], bfr[j], acc[i][j]);
    }
  }
#undef STAGE
#undef UPDATE

  // epilogue: m = pix (A rows), n = co (B rows)
  int px0 = bp * 128 + wm * 64 + ((lane >> 4) << 2);
  int co0 = cot * 128 + wn * 64 + (lane & 15);
#pragma unroll
  for (int j = 0; j < 4; j++) {
    int co = co0 + j * 16;
    float bs = bias[co];
#pragma unroll
    for (int i = 0; i < 4; i++) {
#pragma unroll
      for (int r = 0; r < 4; r++) {
        float v = acc[i][j][r] + bs;
        int pix = px0 + i * 16 + r;
        if (OUT_TRANS_BF16)
          ((unsigned short*)outp)[((((size_t)b << 12) + pix) << 8) + co] = f2bf(v);
        else
          ((float*)outp)[((((size_t)b << 8) + co) << 12) + pix] = v;
      }
    }
  }
}

// ---------- fused instance norm + swish + xd 64->32 downsample ----------
__global__ __launch_bounds__(256) void k_post(float* __restrict__ x, float* __restrict__ xd) {
  __shared__ float sL[4096];
  __shared__ float s4[4];
  int bc = blockIdx.x;
  float* p = x + (size_t)bc * NPIX;
  int tid = threadIdx.x;
  int lane = tid & 63, w = tid >> 6;
  float v[16];
  float s = 0.f;
#pragma unroll
  for (int i = 0; i < 16; i++) { v[i] = p[tid + i * 256]; s += v[i]; }
  s = wave_reduce_sum(s);
  if (lane == 0) s4[w] = s;
  __syncthreads();
  float mean = (s4[0] + s4[1] + s4[2] + s4[3]) * (1.0f / 4096.0f);
  __syncthreads();
  float s2 = 0.f;
#pragma unroll
  for (int i = 0; i < 16; i++) { float d = v[i] - mean; s2 += d * d; }
  s2 = wave_reduce_sum(s2);
  if (lane == 0) s4[w] = s2;
  __syncthreads();
  float var = (s4[0] + s4[1] + s4[2] + s4[3]) * (1.0f / 4096.0f);
  float inv = 1.0f / sqrtf(var + 1e-5f);
#pragma unroll
  for (int i = 0; i < 16; i++) {
    float xn = (v[i] - mean) * inv;
    float sg = 1.0f / (1.0f + expf(-xn));
    float o = xn * sg;
    p[tid + i * 256] = o;
    sL[tid + i * 256] = o;
  }
  __syncthreads();
  float dyx = 63.0f / 31.0f;
  float* xdp = xd + (size_t)bc * NP;
#pragma unroll
  for (int k = 0; k < 4; k++) {
    int q = tid + k * 256;
    int yq = q >> 5, xq = q & 31;
    float yf = (float)yq * dyx;
    float xf = (float)xq * dyx;
    float y0f = floorf(yf), x0f = floorf(xf);
    int y0 = (int)y0f, x0 = (int)x0f;
    int y1 = min(y0 + 1, 63), x1 = min(x0 + 1, 63);
    float wy = yf - y0f, wx = xf - x0f;
    float a = sL[y0 * 64 + x0], b2 = sL[y0 * 64 + x1];
    float c2 = sL[y1 * 64 + x0], d2 = sL[y1 * 64 + x1];
    float top = a * (1.0f - wx) + b2 * wx;
    float bot = c2 * (1.0f - wx) + d2 * wx;
    xdp[q] = top * (1.0f - wy) + bot * wy;
  }
}

// ---------- xd f32 [b][ci][qpix] -> xdt bf16 [b][qpix][ci] ----------
__global__ __launch_bounds__(256) void k_trans_xd(const float* __restrict__ xd,
                                                  unsigned short* __restrict__ xdt) {
  __shared__ unsigned short T[64][66];
  int qt = blockIdx.x, ct = blockIdx.y, b = blockIdx.z;
  int q0 = qt << 6, ci0 = ct << 6;
  int tid = threadIdx.x;
  {
    int r = tid >> 2, c4 = (tid & 3) << 4;
    const float* xb = xd + (((size_t)(b * 256 + ci0 + r)) << 10) + q0 + c4;
#pragma unroll
    for (int k = 0; k < 16; k += 4) {
      float4 f = *(const float4*)(xb + k);
      T[r][c4 + k + 0] = f2bf(f.x);
      T[r][c4 + k + 1] = f2bf(f.y);
      T[r][c4 + k + 2] = f2bf(f.z);
      T[r][c4 + k + 3] = f2bf(f.w);
    }
  }
  __syncthreads();
  {
    int qr = tid >> 2, cc = (tid & 3) << 4;
    unsigned int o[8];
#pragma unroll
    for (int k = 0; k < 8; k++) o[k] = pk2(T[cc + 2 * k][qr], T[cc + 2 * k + 1][qr]);
    size_t ob = ((((size_t)b << 10) + q0 + qr) << 8) + ci0 + cc;
    *(uint4*)&xdt[ob] = *(uint4*)&o[0];
    *(uint4*)&xdt[ob + 8] = *(uint4*)&o[4];
  }
}

// ---------- per-pixel channel sum of squares (128 blocks: 64 pix x 4 ch-groups) ----------
__global__ __launch_bounds__(256) void k_sq32(const float* __restrict__ xd, float* __restrict__ sq) {
  __shared__ float part[256];
  int pg = blockIdx.x;        // 16 pixel-groups of 64
  int b = blockIdx.y;         // 8 batches
  int tid = threadIdx.x;
  int px = tid & 63, g = tid >> 6;
  int pix = pg * 64 + px;
  const float* p = xd + (((size_t)b * C_) << 10) + pix;
  float s = 0.f;
  int c0 = g * 64;
  for (int c = c0; c < c0 + 64; c++) {
    float v = p[(size_t)c << 10];
    s += v * v;
  }
  part[tid] = s;
  __syncthreads();
  if (g == 0) {
    float t = part[px] + part[px + 64] + part[px + 128] + part[px + 192];
    sq[(b << 10) + pix] = t;
  }
}

// ---------- fq[q] = mm ? 1/max(norm,1e-4) : 0 ----------
__global__ __launch_bounds__(256) void k_fq(const float* __restrict__ sq, const float* __restrict__ m64,
                                            float* __restrict__ fq) {
  int idx = blockIdx.x * 256 + threadIdx.x;
  if (idx >= B_ * NP) return;
  int q = idx & 1023, b = idx >> 10;
  int qi = q >> 5, qj = q & 31;
  const float* mb = m64 + (b << 12);
  float dyx = 63.0f / 31.0f;
  float ns = 0.f, ms = 0.f;
#pragma unroll
  for (int k = 0; k < 3; k++)
#pragma unroll
    for (int l = 0; l < 3; l++) {
      int r = qi + k - 1, c = qj + l - 1;
      if (r >= 0 && r < 32 && c >= 0 && c < 32) {
        ns += sq[b * NP + r * 32 + c];
        float yf = (float)r * dyx, xf = (float)c * dyx;
        float y0f = floorf(yf), x0f = floorf(xf);
        int y0 = (int)y0f, x0 = (int)x0f;
        int y1 = min(y0 + 1, 63), x1 = min(x0 + 1, 63);
        float wy = yf - y0f, wx = xf - x0f;
        float a = mb[y0 * 64 + x0], b2 = mb[y0 * 64 + x1];
        float c2 = mb[y1 * 64 + x0], d2 = mb[y1 * 64 + x1];
        float top = a * (1.0f - wx) + b2 * wx;
        float bot = c2 * (1.0f - wx) + d2 * wx;
        ms += top * (1.0f - wy) + bot * wy;
      }
    }
  float f = (ms == 0.0f) ? (1.0f / fmaxf(sqrtf(ns), 1e-4f)) : 0.0f;
  fq[idx] = f;
}

// ---------- Gram, 2-phase GLL16 pipeline BK=64 (R8 verbatim) ----------
__global__ __launch_bounds__(256, 2) void k_gram2ph(const unsigned short* __restrict__ xdt,
                                                    const float* __restrict__ fq,
                                                    const unsigned short* __restrict__ zp,
                                                    float* __restrict__ sc) {
  __shared__ __align__(16) unsigned short AB[2][16384];
  int wgl = blockIdx.x + 8 * (blockIdx.y + 8 * blockIdx.z);
  int nid = (wgl & 7) * 64 + (wgl >> 3);
  int bp = nid & 7, bq = (nid >> 3) & 7, b = nid >> 6;
  int tid = threadIdx.x, lane = tid & 63, w3 = tid >> 6;
  int wm = w3 >> 1, wn = w3 & 1;

  int rA = w3 * 32 + (lane >> 2), rA1 = rA + 16;
  int ds0 = (lane & 3) ^ (rA & 3) ^ ((rA >> 2) & 3);
  int ds1 = (lane & 3) ^ (rA1 & 3) ^ ((rA1 >> 2) & 3);
  int pA0r = bp * 128 + rA, pA1r = bp * 128 + rA1;
  int pB0r = bq * 128 + rA, pB1r = bq * 128 + rA1;
  int piA0 = pA0r >> 5, pjA0 = pA0r & 31, piA1 = pA1r >> 5, pjA1 = pA1r & 31;
  int piB0 = pB0r >> 5, pjB0 = pB0r & 31, piB1 = pB1r >> 5, pjB1 = pB1r & 31;
  const unsigned short* xb = xdt + (((size_t)b) << 18);

  f32x4 acc[4][4];
#pragma unroll
  for (int i = 0; i < 4; i++)
#pragma unroll
    for (int j = 0; j < 4; j++) acc[i][j] = (f32x4){0.f, 0.f, 0.f, 0.f};

  const unsigned short *pA0, *pA1, *pB0, *pB1;

#define GUPDATE(kkv) {                                                          \
    int kk_ = (kkv);                                                            \
    int dy_ = kk_ / 3 - 1, dx_ = kk_ % 3 - 1;                                   \
    int ya0 = piA0 + dy_, xa0 = pjA0 + dx_;                                     \
    int ya1 = piA1 + dy_, xa1 = pjA1 + dx_;                                     \
    int yb0 = piB0 + dy_, xb0 = pjB0 + dx_;                                     \
    int yb1 = piB1 + dy_, xb1 = pjB1 + dx_;                                     \
    pA0 = ((unsigned)ya0 < 32u && (unsigned)xa0 < 32u)                          \
        ? xb + ((((size_t)ya0 << 5) + xa0) << 8) + ds0 * 8 : zp + ds0 * 8;      \
    pA1 = ((unsigned)ya1 < 32u && (unsigned)xa1 < 32u)                          \
        ? xb + ((((size_t)ya1 << 5) + xa1) << 8) + ds1 * 8 : zp + ds1 * 8;      \
    pB0 = ((unsigned)yb0 < 32u && (unsigned)xb0 < 32u)                          \
        ? xb + ((((size_t)yb0 << 5) + xb0) << 8) + ds0 * 8 : zp + ds0 * 8;      \
    pB1 = ((unsigned)yb1 < 32u && (unsigned)xb1 < 32u)                          \
        ? xb + ((((size_t)yb1 << 5) + xb1) << 8) + ds1 * 8 : zp + ds1 * 8;      \
  }
#define GSTAGE(c2, buf) {                                                       \
    int ci0_ = ((c2) & 3) << 6;                                                 \
    unsigned short* lb_ = &AB[buf][0];                                          \
    GLL16(pA0 + ci0_,      lb_ + w3 * 1024);                                    \
    GLL16(pA1 + ci0_,      lb_ + w3 * 1024 + 512);                              \
    GLL16(pA0 + ci0_ + 32, lb_ + 4096 + w3 * 1024);                             \
    GLL16(pA1 + ci0_ + 32, lb_ + 4096 + w3 * 1024 + 512);                       \
    GLL16(pB0 + ci0_,      lb_ + 8192 + w3 * 1024);                             \
    GLL16(pB1 + ci0_,      lb_ + 8192 + w3 * 1024 + 512);                       \
    GLL16(pB0 + ci0_ + 32, lb_ + 12288 + w3 * 1024);                            \
    GLL16(pB1 + ci0_ + 32, lb_ + 12288 + w3 * 1024 + 512);                      \
  }

  GUPDATE(0);
  GSTAGE(0, 0);
  for (int c = 0; c < 36; ++c) {
    asm volatile("" ::: "memory");
    __builtin_amdgcn_s_barrier();
    asm volatile("" ::: "memory");
    if (c < 35) {
      int cn = c + 1;
      if ((cn & 3) == 0) GUPDATE(cn >> 2);
      GSTAGE(cn, cn & 1);
      asm volatile("s_waitcnt vmcnt(8)" ::: "memory");
    } else {
      asm volatile("s_waitcnt vmcnt(0)" ::: "memory");
    }
    __builtin_amdgcn_s_barrier();
    asm volatile("" ::: "memory");
    int slot = lane >> 4;
    int mr = wm * 64 + (lane & 15), ncc = wn * 64 + (lane & 15);
#pragma unroll
    for (int ks = 0; ks < 2; ++ks) {
      const unsigned short* Al = &AB[c & 1][ks << 12];
      const unsigned short* Bl = &AB[c & 1][8192 + (ks << 12)];
      bf16x8 af[4], bfr[4];
#pragma unroll
      for (int i = 0; i < 4; i++) af[i] = *(const bf16x8*)&Al[swz(mr + i * 16, slot)];
#pragma unroll
      for (int j = 0; j < 4; j++) bfr[j] = *(const bf16x8*)&Bl[swz(ncc + j * 16, slot)];
#pragma unroll
      for (int i = 0; i < 4; i++)
#pragma unroll
        for (int j = 0; j < 4; j++)
          acc[i][j] = MFMA16(af[i], bfr[j], acc[i][j]);
    }
  }
#undef GSTAGE
#undef GUPDATE

  int q0 = bq * 128 + wn * 64 + (lane & 15);
  int p0 = bp * 128 + wm * 64 + ((lane >> 4) << 2);
#pragma unroll
  for (int j = 0; j < 4; j++) {
    int q = q0 + j * 16;
    float f = fq[(b << 10) + q];
#pragma unroll
    for (int i = 0; i < 4; i++)
#pragma unroll
      for (int r = 0; r < 4; r++)
        sc[((size_t)(b << 10) + (p0 + i * 16 + r)) * NP + q] = acc[i][j][r] * f;
  }
}

// ---------- softmax over q; emits att bf16 ----------
__global__ __launch_bounds__(256) void k_softmax(const float* __restrict__ sc, const float* __restrict__ fq,
                                                 unsigned short* __restrict__ attb) {
  __shared__ float s4[4];
  int row = blockIdx.x;
  int b = row >> 10;
  const float* r = sc + (size_t)row * NP;
  int tid = threadIdx.x;
  int lane = tid & 63, w = tid >> 6;
  float4 sv = *(const float4*)&r[tid * 4];
  float l0 = sv.x * 10.f, l1 = sv.y * 10.f, l2 = sv.z * 10.f, l3 = sv.w * 10.f;
  float mx = fmaxf(fmaxf(l0, l1), fmaxf(l2, l3));
  mx = wave_reduce_max(mx);
  if (lane == 0) s4[w] = mx;
  __syncthreads();
  float M = fmaxf(fmaxf(s4[0], s4[1]), fmaxf(s4[2], s4[3]));
  __syncthreads();
  float e0 = expf(l0 - M), e1 = expf(l1 - M), e2 = expf(l2 - M), e3 = expf(l3 - M);
  float s = e0 + e1 + e2 + e3;
  s = wave_reduce_sum(s);
  if (lane == 0) s4[w] = s;
  __syncthreads();
  float inv = 1.0f / (s4[0] + s4[1] + s4[2] + s4[3]);
  const float* fb = fq + b * NP + tid * 4;
  float m0 = fb[0] > 0.f ? 1.f : 0.f;
  float m1 = fb[1] > 0.f ? 1.f : 0.f;
  float m2 = fb[2] > 0.f ? 1.f : 0.f;
  float m3 = fb[3] > 0.f ? 1.f : 0.f;
  float a0 = fmaxf(e0 * inv * m0, 1e-8f);
  float a1 = fmaxf(e1 * inv * m1, 1e-8f);
  float a2 = fmaxf(e2 * inv * m2, 1e-8f);
  float a3 = fmaxf(e3 * inv * m3, 1e-8f);
  uint2 o;
  o.x = pk2(f2bf(a0), f2bf(a1));
  o.y = pk2(f2bf(a2), f2bf(a3));
  *(uint2*)&attb[(size_t)row * NP + tid * 4] = o;
}

// ---------- x -> parity-split pre-shifted bf16 copies P0/P1/P2 ----------
__global__ __launch_bounds__(256) void k_xprep(const float* __restrict__ x,
                                               unsigned short* __restrict__ P0,
                                               unsigned short* __restrict__ P1,
                                               unsigned short* __restrict__ P2) {
  int idx = blockIdx.x * 256 + threadIdx.x;
  int xh8 = idx & 3;
  int yh = (idx >> 2) & 31;
  int co = (idx >> 7) & 255;
  int pc = (idx >> 15) & 3;
  int b  = idx >> 17;
  int cy = pc >> 1, cx = pc & 1;
  const float* row = x + ((size_t)(b * 256 + co) * 64 + (2 * yh + cy)) * 64 + 16 * xh8;
  float4 f0 = *(const float4*)(row);
  float4 f1 = *(const float4*)(row + 4);
  float4 f2 = *(const float4*)(row + 8);
  float4 f3 = *(const float4*)(row + 12);
  unsigned short v0 = f2bf(cx ? f0.y : f0.x), v1 = f2bf(cx ? f0.w : f0.z);
  unsigned short v2 = f2bf(cx ? f1.y : f1.x), v3 = f2bf(cx ? f1.w : f1.z);
  unsigned short v4 = f2bf(cx ? f2.y : f2.x), v5 = f2bf(cx ? f2.w : f2.z);
  unsigned short v6 = f2bf(cx ? f3.y : f3.x), v7 = f2bf(cx ? f3.w : f3.z);
  int prev = __shfl_up((int)v7, 1, 64);
  int next = __shfl_down((int)v0, 1, 64);
  unsigned short pv = (xh8 == 0) ? (unsigned short)0 : (unsigned short)prev;
  unsigned short nx = (xh8 == 3) ? (unsigned short)0 : (unsigned short)next;
  size_t base = ((size_t)((b * 4 + pc) * 256 + co) * 32 + yh) * 32 + 8 * xh8;
  uint4 w0 = {pk2(v0, v1), pk2(v2, v3), pk2(v4, v5), pk2(v6, v7)};
  *(uint4*)&P0[base] = w0;
  uint4 w1 = {pk2(pv, v0), pk2(v1, v2), pk2(v3, v4), pk2(v5, v6)};
  *(uint4*)&P1[base] = w1;
  uint4 w2 = {pk2(v1, v2), pk2(v3, v4), pk2(v5, v6), pk2(v7, nx)};
  *(uint4*)&P2[base] = w2;
}

// ---------- PV class-GEMM, 2-phase counted-vmcnt pipeline BK=64 (R8 verbatim) ----------
__global__ __launch_bounds__(256, 2) void k_pv(const unsigned short* __restrict__ attb,
                                               const unsigned short* __restrict__ P0,
                                               const unsigned short* __restrict__ P1,
                                               const unsigned short* __restrict__ P2,
                                               const unsigned short* __restrict__ zp,
                                               const float* __restrict__ xbuf,
                                               const float* __restrict__ m64,
                                               float* __restrict__ out) {
  __shared__ __align__(16) unsigned short AB[2][16384];
  int wg = blockIdx.x + blockIdx.y * 8 + blockIdx.z * 16;
  int nid = (wg & 7) * 64 + (wg >> 3);
  int bn = nid & 7, bm = (nid >> 3) & 1, z = nid >> 4;
  int b = z >> 2, cls = z & 3, cy = cls >> 1, cx = cls & 1;
  int tid = threadIdx.x, lane = tid & 63, w3 = tid >> 6;
  int wm = w3 >> 1, wn = w3 & 1;

  int dy1 = cy ? -1 : 1;
  int pio1 = cy ? 1 : -1;
  int pjo1 = cx ? 1 : -1;
  const unsigned short* Pdx = cx ? P1 : P2;

  int rA0 = w3 * 32 + (lane >> 2);
  int rA1 = rA0 + 16;
  int ds0 = (lane & 3) ^ (rA0 & 3) ^ ((rA0 >> 2) & 3);
  int ds1 = (lane & 3) ^ (rA1 & 3) ^ ((rA1 >> 2) & 3);
  int offA0 = ((z * 256 + bm * 128 + rA0) << 10) + ds0 * 8;
  int offA1 = ((z * 256 + bm * 128 + rA1) << 10) + ds1 * 8;

  const unsigned short* attB = attb + ((size_t)b << 20);
  int o0 = bn * 128 + rA0, o1 = bn * 128 + rA1;
  int oy0 = o0 >> 5, ox0 = o0 & 31, oy1 = o1 >> 5, ox1 = o1 & 31;
#define BPTR(oyv, oxv, dsv, tyv, txv) ({                                        \
    int pi = (oyv) + ((tyv) ? pio1 : 0);                                        \
    int pj = (oxv) + ((txv) ? pjo1 : 0);                                        \
    (pi >= 0 && pi < 32 && pj >= 0 && pj < 32)                                  \
        ? attB + (((pi << 5) + pj) << 10) + (dsv) * 8 : zp; })
  const unsigned short* b0t0 = BPTR(oy0, ox0, ds0, 0, 0);
  const unsigned short* b0t1 = BPTR(oy0, ox0, ds0, 0, 1);
  const unsigned short* b0t2 = BPTR(oy0, ox0, ds0, 1, 0);
  const unsigned short* b0t3 = BPTR(oy0, ox0, ds0, 1, 1);
  const unsigned short* b1t0 = BPTR(oy1, ox1, ds1, 0, 0);
  const unsigned short* b1t1 = BPTR(oy1, ox1, ds1, 0, 1);
  const unsigned short* b1t2 = BPTR(oy1, ox1, ds1, 1, 0);
  const unsigned short* b1t3 = BPTR(oy1, ox1, ds1, 1, 1);
#undef BPTR

  f32x4 acc[4][4];
#pragma unroll
  for (int i = 0; i < 4; i++)
#pragma unroll
    for (int j = 0; j < 4; j++) acc[i][j] = (f32x4){0.f, 0.f, 0.f, 0.f};

  int dA0 = w3 * 1024, dA1 = w3 * 1024 + 512;
  int dB0 = 8192 + w3 * 1024, dB1 = 8192 + w3 * 1024 + 512;

#define PHALF(o2, buf, h) {                                                     \
    int t2 = (o2) >> 5, qi = (o2) & 31;                                         \
    int q32 = qi * 32;                                                          \
    const unsigned short* Ab = (t2 & 1) ? Pdx : P0;                             \
    int dyo = (t2 >> 1) ? dy1 * 32 : 0;                                         \
    bool vA = (t2 < 2) || ((dy1 > 0) ? (qi < 31) : (qi > 0));                   \
    if (!vA) Ab = zp;                                                           \
    int oA0 = vA ? offA0 + dyo + q32 : 0;                                       \
    int oA1 = vA ? offA1 + dyo + q32 : 0;                                       \
    unsigned short* lb = &AB[buf][(h) << 12];                                   \
    GLL16(Ab + oA0, lb + dA0);                                                  \
    GLL16(Ab + oA1, lb + dA1);                                                  \
    const unsigned short* sB0 = (t2 == 0 ? b0t0 : t2 == 1 ? b0t1 : t2 == 2 ? b0t2 : b0t3) + q32; \
    const unsigned short* sB1 = (t2 == 0 ? b1t0 : t2 == 1 ? b1t1 : t2 == 2 ? b1t2 : b1t3) + q32; \
    GLL16(sB0, lb + dB0);                                                       \
    GLL16(sB1, lb + dB1);                                                       \
  }
#define PSTAGE(c2, buf) { PHALF(2 * (c2), buf, 0); PHALF(2 * (c2) + 1, buf, 1); }

  PSTAGE(0, 0);
  for (int c = 0; c < 64; ++c) {
    asm volatile("" ::: "memory");
    __builtin_amdgcn_s_barrier();
    asm volatile("" ::: "memory");
    if (c < 63) {
      PSTAGE(c + 1, (c + 1) & 1);
      asm volatile("s_waitcnt vmcnt(8)" ::: "memory");
    } else {
      asm volatile("s_waitcnt vmcnt(0)" ::: "memory");
    }
    __builtin_amdgcn_s_barrier();
    asm volatile("" ::: "memory");
    int slot = lane >> 4;
    int mr = wm * 64 + (lane & 15), ncc = wn * 64 + (lane & 15);
#pragma unroll
    for (int ks = 0; ks < 2; ++ks) {
      const unsigned short* Al = &AB[c & 1][ks << 12];
      const unsigned short* Bl = &AB[c & 1][8192 + (ks << 12)];
      bf16x8 af[4], bfr[4];
#pragma unroll
      for (int i = 0; i < 4; i++) af[i] = *(const bf16x8*)&Al[swz(mr + i * 16, slot)];
#pragma unroll
      for (int j = 0; j < 4; j++) bfr[j] = *(const bf16x8*)&Bl[swz(ncc + j * 16, slot)];
#pragma unroll
      for (int i = 0; i < 4; i++)
#pragma unroll
        for (int j = 0; j < 4; j++)
          acc[i][j] = MFMA16(af[i], bfr[j], acc[i][j]);
    }
  }
#undef PSTAGE
#undef PHALF

  int co0 = bm * 128 + wm * 64 + ((lane >> 4) << 2);
  int oo0 = bn * 128 + wn * 64 + (lane & 15);
#pragma unroll
  for (int j = 0; j < 4; j++) {
    int o = oo0 + j * 16;
    int oy = ((o >> 5) << 1) + cy, ox = ((o & 31) << 1) + cx;
    int opix = oy * 64 + ox;
    float msk = m64[b * NPIX + opix];
    float s = 0.25f * msk, t1m = 1.0f - msk;
#pragma unroll
    for (int i = 0; i < 4; i++) {
#pragma unroll
      for (int r = 0; r < 4; r++) {
        int co = co0 + i * 16 + r;
        size_t xi = (size_t)(b * C_ + co) * NPIX + opix;
        out[xi] = acc[i][j][r] * s + xbuf[xi] * t1m;
      }
    }
  }
}

extern "C" void kernel_launch(void* const* d_in, const int* in_sizes, int n_in,
                              void* d_out, int out_size, void* d_ws, size_t ws_size,
                              hipStream_t stream) {
  const float* bg   = (const float*)d_in[0];
  const float* fg   = (const float*)d_in[1];
  const float* mask = (const float*)d_in[2];
  const float* Wc   = (const float*)d_in[3];
  const float* bc   = (const float*)d_in[4];
  const float* Wm   = (const float*)d_in[5];
  const float* bm   = (const float*)d_in[6];
  const float* Wf   = (const float*)d_in[7];
  const float* bf   = (const float*)d_in[8];
  float* out = (float*)d_out;
  float* w = (float*)d_ws;

  // workspace (float offsets), total 25,231,360 floats = 100.9 MB
  float* mask64 = w;                          // 32768
  float* sq32   = w + 40960;                  // 8192
  float* fq     = w + 49152;                  // 8192
  float* bias1  = w + 57344;                  // 256
  float* zpage  = w + 57600;                  // 2048 zeros (8 KB)
  unsigned short* A0t = (unsigned short*)(w + 65536);            // [b][pix][ci]
  unsigned short* A1t = (unsigned short*)(w + 65536 + 4194304);
  float* sc = w + 65536;
  unsigned short* P0u = (unsigned short*)(w + 65536);
  unsigned short* P1u = (unsigned short*)(w + 4259840);
  unsigned short* tbuf_t = (unsigned short*)(w + 8454144);       // [b][pix][co]
  float* xd = w + 8454144;
  unsigned short* xdt = (unsigned short*)(w + 10551296);
  unsigned short* attb = (unsigned short*)(w + 8454144);
  float* xbuf = w + 12648448;
  unsigned short* Wp1 = (unsigned short*)(w + 21037056);
  unsigned short* Wp2 = (unsigned short*)(w + 21626880);
  unsigned short* P2u = (unsigned short*)(w + 21037056);

  const unsigned short* zp = (const unsigned short*)zpage;

  hipLaunchKernelGGL(k_resize, dim3(128), dim3(256), 0, stream, mask, mask64, 256, 256, 64, 64, 32768);
  hipLaunchKernelGGL(k_wprep, dim3(6913), dim3(256), 0, stream, Wc, Wm, Wf, Wp1, Wp2, bc, bm, bias1, zpage);
  hipLaunchKernelGGL(k_prepAT, dim3(64, 4, 8), dim3(256), 0, stream, fg, bg, mask64, A0t, A1t);
  // conv1 (K=4608) -> tbuf_t bf16 [pix][co]
  hipLaunchKernelGGL((k_conv2ph<18, true>), dim3(32, 2, 8), dim3(256), 0, stream,
                     A0t, A1t, Wp1, bias1, zp, (void*)tbuf_t);
  // conv2 (K=2304) -> xbuf f32 [co][pix]
  hipLaunchKernelGGL((k_conv2ph<9, false>), dim3(32, 2, 8), dim3(256), 0, stream,
                     tbuf_t, tbuf_t, Wp2, bf, zp, (void*)xbuf);
  hipLaunchKernelGGL(k_post, dim3(B_ * C_), dim3(256), 0, stream, xbuf, xd);
  hipLaunchKernelGGL(k_trans_xd, dim3(16, 4, 8), dim3(256), 0, stream, xd, xdt);
  hipLaunchKernelGGL(k_sq32, dim3(16, 8), dim3(256), 0, stream, xd, sq32);
  hipLaunchKernelGGL(k_fq, dim3(32), dim3(256), 0, stream, sq32, mask64, fq);
  hipLaunchKernelGGL(k_gram2ph, dim3(8, 8, 8), dim3(256), 0, stream, xdt, fq, zp, sc);
  hipLaunchKernelGGL(k_softmax, dim3(B_ * NP), dim3(256), 0, stream, sc, fq, attb);
  hipLaunchKernelGGL(k_xprep, dim3(4096), dim3(256), 0, stream, xbuf, P0u, P1u, P2u);
  hipLaunchKernelGGL(k_pv, dim3(8, 2, 32), dim3(256), 0, stream, attb, P0u, P1u, P2u,
                     zp, xbuf, mask64, out);
}